// Round 6
// baseline (212.247 us; speedup 1.0000x reference)
//
#include <hip/hip_runtime.h>
#include <math.h>

#define EPS 1e-7f

constexpr int B = 16, L = 1024, D = 256, P = 20;
constexpr int LD = L * D;     // 262144
constexpr int DD = D * D;     // 65536

typedef __attribute__((ext_vector_type(8))) short bf16x8;
typedef __attribute__((ext_vector_type(4))) float f32x4;

// ---------------------------------------------------------------------------
// ws layout (float slots):
//   n1    @0         16384     fp32 [B*L]
//   invn2 @16384     16384     fp32 [B*L]
//   t     @32768     4096      fp32 [B*D]   (memset 0, atomic)
//   invU  @36864     16384     fp32 [B*L]   1/(s1.t + eps*n1)
//   rnv1  @53248     327680    fp32 [B*L][P] 1/sqrt(max(sum s1^2 k2,eps))
//   s1h   @380928    2097152   bf16 [B*L][D]
//   s1l   @2478080   2097152   bf16 [B*L][D]
//   ChT   @4575232   2097152   bf16 [B][D][L]  (s2*sqrt(invn2), transposed, hi)
//   ClT   @6672384   2097152   bf16 [B][D][L]  (lo)
//   Gh    @8769536   524288    bf16 [B][D][D]
//   Gl    @9293824   524288    bf16 [B][D][D]
//   Gp    @9818112   4194304   fp32 [4][B][D][D]  gram K-split partials
// total 14012416 floats = 56 MB
// ---------------------------------------------------------------------------

__device__ inline void bf16split(float x, unsigned short &h, unsigned short &l) {
    union { float f; unsigned u; } a; a.f = x;
    unsigned hu = (a.u + 0x7FFFu + ((a.u >> 16) & 1u)) & 0xFFFF0000u;
    union { unsigned u; float f; } hb; hb.u = hu;
    h = (unsigned short)(hu >> 16);
    float r = x - hb.f;
    union { float f; unsigned u; } c; c.f = r;
    l = (unsigned short)((c.u + 0x7FFFu + ((c.u >> 16) & 1u)) >> 16);
}

// K1: per-row L2 norms; also emits bf16 hi/lo split of s1 (natural layout).
__global__ __launch_bounds__(256) void k_norms(const float* __restrict__ s1,
                                               const float* __restrict__ s2,
                                               float* __restrict__ n1,
                                               float* __restrict__ invn2,
                                               unsigned short* __restrict__ s1h,
                                               unsigned short* __restrict__ s1l) {
    int tid  = threadIdx.x;
    int lane = tid & 63, w = tid >> 6;
    int row  = blockIdx.x * 4 + w;            // 0..32767
    int r    = (row < B * L) ? row : row - B * L;
    const float* src = (row < B * L) ? s1 : s2;
    float4 v = *(const float4*)(src + (size_t)r * D + lane * 4);
    float s = v.x * v.x + v.y * v.y + v.z * v.z + v.w * v.w;
#pragma unroll
    for (int o = 32; o; o >>= 1) s += __shfl_down(s, o);
    if (row < B * L) {
        ushort4 h4, l4;
        bf16split(v.x, h4.x, l4.x);
        bf16split(v.y, h4.y, l4.y);
        bf16split(v.z, h4.z, l4.z);
        bf16split(v.w, h4.w, l4.w);
        *(ushort4*)(s1h + (size_t)r * D + lane * 4) = h4;
        *(ushort4*)(s1l + (size_t)r * D + lane * 4) = l4;
    }
    if (lane == 0) {
        float n = sqrtf(fmaxf(s, EPS));
        if (row < B * L) n1[r] = n;
        else             invn2[r] = 1.0f / n;
    }
}

// K2: t[b,d] = sum_m s2[b,m,d] * invn2[b,m].
__global__ __launch_bounds__(256) void k_t(const float* __restrict__ s2,
                                           const float* __restrict__ invn2,
                                           float* __restrict__ t) {
    int b  = blockIdx.x >> 5;
    int mc = blockIdx.x & 31;
    int d  = threadIdx.x;
    const float* sp = s2 + (size_t)b * LD + (size_t)mc * 32 * D + d;
    const float* wp = invn2 + b * L + mc * 32;
    float acc = 0.f;
#pragma unroll 4
    for (int m = 0; m < 32; ++m) acc += sp[(size_t)m * D] * wp[m];
    atomicAdd(&t[b * D + d], acc);
}

// K2b: invU[row] = 1/(s1[row].t[b] + eps*n1) AND rnv1[row][p] = rsqrt(max(s1^2.k2p, eps))
__global__ __launch_bounds__(256) void k_u(const float* __restrict__ s1,
                                           const float* __restrict__ t,
                                           const float* __restrict__ n1,
                                           const float* __restrict__ kern,
                                           float* __restrict__ invU,
                                           float* __restrict__ rnv1) {
    __shared__ float k2s[P * D];   // 20 KB
    int tid = threadIdx.x;
#pragma unroll
    for (int p = 0; p < P; ++p) {
        float v = kern[p * D + tid];
        k2s[p * D + tid] = v * v;
    }
    __syncthreads();

    int w = tid >> 6, lane = tid & 63;
    int row = blockIdx.x * 4 + w;             // 0..16383
    int b   = row >> 10;
    int dg = lane & 15, ps = lane >> 4;

    float4 sv[4], ss[4];
    float up = 0.f;
#pragma unroll
    for (int j = 0; j < 4; ++j) {
        sv[j] = *(const float4*)(s1 + (size_t)row * D + dg * 4 + j * 64);
        float4 tv = *(const float4*)(t + b * D + dg * 4 + j * 64);
        up += sv[j].x * tv.x + sv[j].y * tv.y + sv[j].z * tv.z + sv[j].w * tv.w;
        ss[j].x = sv[j].x * sv[j].x; ss[j].y = sv[j].y * sv[j].y;
        ss[j].z = sv[j].z * sv[j].z; ss[j].w = sv[j].w * sv[j].w;
    }
#pragma unroll
    for (int o = 8; o; o >>= 1) up += __shfl_down(up, o, 16);
    if (dg == 0 && ps == 0) invU[row] = 1.0f / (up + EPS * n1[row]);
#pragma unroll
    for (int tI = 0; tI < 5; ++tI) {
        int p = ps + tI * 4;
        float nb = 0.f;
#pragma unroll
        for (int j = 0; j < 4; ++j) {
            float4 kv = *(const float4*)&k2s[p * D + j * 64 + dg * 4];
            nb += ss[j].x * kv.x + ss[j].y * kv.y + ss[j].z * kv.z + ss[j].w * kv.w;
        }
#pragma unroll
        for (int o = 8; o; o >>= 1) nb += __shfl_down(nb, o, 16);
        if (dg == 0) rnv1[(size_t)row * P + p] = rsqrtf(fmaxf(nb, EPS));
    }
}

// K3: transpose+split C = s2*sqrt(invn2) -> ChT/ClT, [B][D][L] bf16 (K=m contig).
__global__ __launch_bounds__(256) void k_split2(const float* __restrict__ s2,
                                                const float* __restrict__ invn2,
                                                unsigned short* __restrict__ ChT,
                                                unsigned short* __restrict__ ClT) {
    __shared__ float tile[64][65];
    __shared__ float wsh[64];
    int tid = threadIdx.x;
    int b   = blockIdx.x >> 6;
    int rem = blockIdx.x & 63;
    int mt  = rem >> 2, dt = rem & 3;
    int m0  = mt * 64, d0 = dt * 64;
    {
        int r = tid >> 2, cs = (tid & 3) * 16;
        const float* gp = s2 + (size_t)b * LD + (size_t)(m0 + r) * D + d0 + cs;
        float4 v0 = ((const float4*)gp)[0];
        float4 v1 = ((const float4*)gp)[1];
        float4 v2 = ((const float4*)gp)[2];
        float4 v3 = ((const float4*)gp)[3];
        *(float4*)&tile[r][cs]      = v0;
        *(float4*)&tile[r][cs + 4]  = v1;
        *(float4*)&tile[r][cs + 8]  = v2;
        *(float4*)&tile[r][cs + 12] = v3;
        if (tid < 64) wsh[tid] = sqrtf(invn2[b * L + m0 + tid]);
    }
    __syncthreads();
    int dc = tid >> 2, ms = (tid & 3) * 16;
    union { unsigned short us[16]; uint4 q[2]; } pCh, pCl;
#pragma unroll
    for (int k = 0; k < 16; ++k) {
        int m = ms + k;
        float wv = tile[m][dc] * wsh[m];
        bf16split(wv, pCh.us[k], pCl.us[k]);
    }
    size_t o = (size_t)b * LD + (size_t)(d0 + dc) * L + m0 + ms;
    *(uint4*)(ChT + o) = pCh.q[0]; *(uint4*)(ChT + o + 8) = pCh.q[1];
    *(uint4*)(ClT + o) = pCl.q[0]; *(uint4*)(ClT + o + 8) = pCl.q[1];
}

// K4: Gram via MFMA.  G = Ch'Ch + Ch'Cl + Cl'Ch (bf16x2), K-split x4.
__global__ __launch_bounds__(256) void k_gram_mfma(const unsigned short* __restrict__ ChT,
                                                   const unsigned short* __restrict__ ClT,
                                                   float* __restrict__ Gp) {
    __shared__ short As[128 * 72];
    __shared__ short Bs[128 * 72];
    int tid  = threadIdx.x;
    int b    = blockIdx.x >> 4;
    int rem  = blockIdx.x & 15;
    int ti   = rem >> 3, tj = (rem >> 2) & 1, kc = rem & 3;
    int wave = tid >> 6, lane = tid & 63;
    int wr   = (wave >> 1) * 64, wc = (wave & 1) * 64;
    int lr   = lane & 15, lq = lane >> 4;
    int srow = tid >> 1, shalf = (tid & 1) * 32;

    f32x4 acc[4][4];
#pragma unroll
    for (int i = 0; i < 4; ++i)
#pragma unroll
        for (int j = 0; j < 4; ++j) acc[i][j] = (f32x4){0.f, 0.f, 0.f, 0.f};

#pragma unroll 1
    for (int tau = 0; tau < 3; ++tau) {
        const unsigned short* Ap = (tau < 2) ? ChT : ClT;
        const unsigned short* Bp = (tau == 1) ? ClT : ChT;
#pragma unroll 1
        for (int kb = 0; kb < 4; ++kb) {
            int koff = kc * 256 + kb * 64 + shalf;
            __syncthreads();
            {
                const unsigned short* ga = Ap + (size_t)b * LD + (size_t)(ti * 128 + srow) * L + koff;
                const unsigned short* gb = Bp + (size_t)b * LD + (size_t)(tj * 128 + srow) * L + koff;
                uint4 a0 = ((const uint4*)ga)[0], a1 = ((const uint4*)ga)[1];
                uint4 a2 = ((const uint4*)ga)[2], a3 = ((const uint4*)ga)[3];
                uint4 b0 = ((const uint4*)gb)[0], b1 = ((const uint4*)gb)[1];
                uint4 b2 = ((const uint4*)gb)[2], b3 = ((const uint4*)gb)[3];
                short* la = &As[srow * 72 + shalf];
                short* lb = &Bs[srow * 72 + shalf];
                ((uint4*)la)[0] = a0; ((uint4*)la)[1] = a1;
                ((uint4*)la)[2] = a2; ((uint4*)la)[3] = a3;
                ((uint4*)lb)[0] = b0; ((uint4*)lb)[1] = b1;
                ((uint4*)lb)[2] = b2; ((uint4*)lb)[3] = b3;
            }
            __syncthreads();
#pragma unroll
            for (int ks = 0; ks < 2; ++ks) {
                bf16x8 af[4], bfr[4];
#pragma unroll
                for (int i = 0; i < 4; ++i)
                    af[i] = *(const bf16x8*)&As[(wr + i * 16 + lr) * 72 + ks * 32 + lq * 8];
#pragma unroll
                for (int j = 0; j < 4; ++j)
                    bfr[j] = *(const bf16x8*)&Bs[(wc + j * 16 + lr) * 72 + ks * 32 + lq * 8];
#pragma unroll
                for (int i = 0; i < 4; ++i)
#pragma unroll
                    for (int j = 0; j < 4; ++j)
                        acc[i][j] = __builtin_amdgcn_mfma_f32_16x16x32_bf16(af[i], bfr[j], acc[i][j], 0, 0, 0);
            }
        }
    }
    float* gout = Gp + ((size_t)(kc * B + b)) * DD;
#pragma unroll
    for (int i = 0; i < 4; ++i) {
#pragma unroll
        for (int r = 0; r < 4; ++r) {
            int row = ti * 128 + wr + i * 16 + lq * 4 + r;
#pragma unroll
            for (int j = 0; j < 4; ++j) {
                int col = tj * 128 + wc + j * 16 + lr;
                gout[(size_t)row * D + col] = acc[i][j][r];
            }
        }
    }
}

// K5: reduce 4 gram partials; emit bf16 hi/lo split of G.
__global__ __launch_bounds__(256) void k_reduceG(const float* __restrict__ Gp,
                                                 unsigned short* __restrict__ Gh,
                                                 unsigned short* __restrict__ Gl) {
    size_t i = ((size_t)blockIdx.x * 256 + threadIdx.x) * 4;
    float4 a = *(const float4*)(Gp + i);
    float4 b = *(const float4*)(Gp + (size_t)B * DD + i);
    float4 c = *(const float4*)(Gp + (size_t)2 * B * DD + i);
    float4 d = *(const float4*)(Gp + (size_t)3 * B * DD + i);
    float4 s;
    s.x = a.x + b.x + c.x + d.x;
    s.y = a.y + b.y + c.y + d.y;
    s.z = a.z + b.z + c.z + d.z;
    s.w = a.w + b.w + c.w + d.w;
    ushort4 h4, l4;
    bf16split(s.x, h4.x, l4.x);
    bf16split(s.y, h4.y, l4.y);
    bf16split(s.z, h4.z, l4.z);
    bf16split(s.w, h4.w, l4.w);
    *(ushort4*)(Gh + i) = h4;
    *(ushort4*)(Gl + i) = l4;
}

// K6 (fused): per block computes u = s1 @ G for a 64(l) x 256(full D) tile
// via MFMA (3-term bf16x2), scales by invU -> mav in LDS, then k_out-style
// epilogue.  Grid: 16 b x 16 lt = 256.  Waves: 2(lrow) x 2(ncol).
union ShMem {
    struct { short As[64 * 72]; short Bs[256 * 72]; } g;
    struct { float mavs[32][264]; float k2s[P * D]; } e;
};
__global__ __launch_bounds__(256) void k_mavout(const unsigned short* __restrict__ s1h,
                                                const unsigned short* __restrict__ s1l,
                                                const unsigned short* __restrict__ Gh,
                                                const unsigned short* __restrict__ Gl,
                                                const float* __restrict__ invU,
                                                const float* __restrict__ rnv1,
                                                const float* __restrict__ s1,
                                                const float* __restrict__ kern,
                                                float* __restrict__ out) {
    __shared__ ShMem sh;
    int tid  = threadIdx.x;
    int b    = blockIdx.x >> 4;
    int lt   = blockIdx.x & 15;
    int l0   = lt * 64;
    int wave = tid >> 6, lane = tid & 63;
    int wrow = wave >> 1, wc = (wave & 1) * 128;
    int lr   = lane & 15, lq = lane >> 4;

    f32x4 acc[2][8];
#pragma unroll
    for (int i = 0; i < 2; ++i)
#pragma unroll
        for (int j = 0; j < 8; ++j) acc[i][j] = (f32x4){0.f, 0.f, 0.f, 0.f};

    int arow = tid >> 2, aq = (tid & 3) * 16;   // A staging: 64 rows x 64 shorts

#pragma unroll 1
    for (int tau = 0; tau < 3; ++tau) {
        const unsigned short* Ap = (tau < 2) ? s1h : s1l;
        const unsigned short* Bp = (tau == 1) ? Gl : Gh;
#pragma unroll 1
        for (int kb = 0; kb < 4; ++kb) {
            int koff = kb * 64;
            __syncthreads();
            {
                const unsigned short* ga = Ap + (size_t)(b * L + l0 + arow) * D + koff + aq;
                uint4 a0 = ((const uint4*)ga)[0], a1 = ((const uint4*)ga)[1];
                // B staging: one full 64-short row per thread (8 uint4 = 128 B)
                const unsigned short* gb = Bp + (size_t)b * DD + (size_t)tid * D + koff;
                uint4 b0 = ((const uint4*)gb)[0], b1 = ((const uint4*)gb)[1];
                uint4 b2 = ((const uint4*)gb)[2], b3 = ((const uint4*)gb)[3];
                uint4 b4 = ((const uint4*)gb)[4], b5 = ((const uint4*)gb)[5];
                uint4 b6 = ((const uint4*)gb)[6], b7 = ((const uint4*)gb)[7];
                short* la = &sh.g.As[arow * 72 + aq];
                ((uint4*)la)[0] = a0; ((uint4*)la)[1] = a1;
                short* lb = &sh.g.Bs[tid * 72];
                ((uint4*)lb)[0] = b0; ((uint4*)lb)[1] = b1;
                ((uint4*)lb)[2] = b2; ((uint4*)lb)[3] = b3;
                ((uint4*)lb)[4] = b4; ((uint4*)lb)[5] = b5;
                ((uint4*)lb)[6] = b6; ((uint4*)lb)[7] = b7;
            }
            __syncthreads();
#pragma unroll
            for (int ks = 0; ks < 2; ++ks) {
                bf16x8 af[2], bfr[8];
#pragma unroll
                for (int i = 0; i < 2; ++i)
                    af[i] = *(const bf16x8*)&sh.g.As[(wrow * 32 + i * 16 + lr) * 72 + ks * 32 + lq * 8];
#pragma unroll
                for (int j = 0; j < 8; ++j)
                    bfr[j] = *(const bf16x8*)&sh.g.Bs[(wc + j * 16 + lr) * 72 + ks * 32 + lq * 8];
#pragma unroll
                for (int i = 0; i < 2; ++i)
#pragma unroll
                    for (int j = 0; j < 8; ++j)
                        acc[i][j] = __builtin_amdgcn_mfma_f32_16x16x32_bf16(af[i], bfr[j], acc[i][j], 0, 0, 0);
            }
        }
    }

    // ---- epilogue ----
    float invu[2][4];
#pragma unroll
    for (int i = 0; i < 2; ++i)
#pragma unroll
        for (int r = 0; r < 4; ++r)
            invu[i][r] = invU[b * L + l0 + wrow * 32 + i * 16 + lq * 4 + r];

    __syncthreads();   // all GEMM LDS reads done; safe to repurpose
#pragma unroll
    for (int p = 0; p < P; ++p) {
        float v = kern[p * D + tid];
        sh.e.k2s[p * D + tid] = v * v;
    }

    int dg = lane & 15, ps = lane >> 4;
#pragma unroll 1
    for (int half = 0; half < 2; ++half) {
        __syncthreads();
        if (wrow == half) {
#pragma unroll
            for (int i = 0; i < 2; ++i)
#pragma unroll
                for (int r = 0; r < 4; ++r) {
                    float iv = invu[i][r];
                    int mrow = i * 16 + lq * 4 + r;
#pragma unroll
                    for (int j = 0; j < 8; ++j)
                        sh.e.mavs[mrow][wc + j * 16 + lr] = acc[i][j][r] * iv;
                }
        }
        __syncthreads();
#pragma unroll 1
        for (int rr = 0; rr < 8; ++rr) {
            int mrow = wave * 8 + rr;
            int gl   = b * L + l0 + half * 32 + mrow;
            float4 mv[4], sv[4], sm[4], mm[4];
#pragma unroll
            for (int j = 0; j < 4; ++j) {
                mv[j] = *(const float4*)&sh.e.mavs[mrow][dg * 4 + j * 64];
                sv[j] = *(const float4*)(s1 + (size_t)gl * D + dg * 4 + j * 64);
                sm[j].x = sv[j].x * mv[j].x; sm[j].y = sv[j].y * mv[j].y;
                sm[j].z = sv[j].z * mv[j].z; sm[j].w = sv[j].w * mv[j].w;
                mm[j].x = mv[j].x * mv[j].x; mm[j].y = mv[j].y * mv[j].y;
                mm[j].z = mv[j].z * mv[j].z; mm[j].w = mv[j].w * mv[j].w;
            }
#pragma unroll
            for (int tI = 0; tI < 5; ++tI) {
                int p = ps + tI * 4;
                float na = 0.f, nc = 0.f;
#pragma unroll
                for (int j = 0; j < 4; ++j) {
                    float4 kv = *(const float4*)&sh.e.k2s[p * D + j * 64 + dg * 4];
                    na += sm[j].x * kv.x + sm[j].y * kv.y + sm[j].z * kv.z + sm[j].w * kv.w;
                    nc += mm[j].x * kv.x + mm[j].y * kv.y + mm[j].z * kv.z + mm[j].w * kv.w;
                }
#pragma unroll
                for (int o = 8; o; o >>= 1) {
                    na += __shfl_down(na, o, 16);
                    nc += __shfl_down(nc, o, 16);
                }
                if (dg == 0) {
                    out[(size_t)gl * P + p] = na * rnv1[(size_t)gl * P + p] *
                                              rsqrtf(fmaxf(nc, EPS));
                }
            }
        }
    }
}

extern "C" void kernel_launch(void* const* d_in, const int* in_sizes, int n_in,
                              void* d_out, int out_size, void* d_ws, size_t ws_size,
                              hipStream_t stream) {
    const float* s1   = (const float*)d_in[0];
    const float* s2   = (const float*)d_in[1];
    const float* kern = (const float*)d_in[2];
    float* out = (float*)d_out;
    float* ws  = (float*)d_ws;

    float* n1    = ws;
    float* invn2 = ws + 16384;
    float* t     = ws + 32768;
    float* invU  = ws + 36864;
    float* rnv1  = ws + 53248;
    unsigned short* s1h = (unsigned short*)(ws + 380928);
    unsigned short* s1l = (unsigned short*)(ws + 2478080);
    unsigned short* ChT = (unsigned short*)(ws + 4575232);
    unsigned short* ClT = (unsigned short*)(ws + 6672384);
    unsigned short* Gh  = (unsigned short*)(ws + 8769536);
    unsigned short* Gl  = (unsigned short*)(ws + 9293824);
    float* Gp  = ws + 9818112;

    hipMemsetAsync(t, 0, (size_t)4096 * sizeof(float), stream);

    k_norms<<<8192, 256, 0, stream>>>(s1, s2, n1, invn2, s1h, s1l);
    k_t<<<512, 256, 0, stream>>>(s2, invn2, t);
    k_u<<<4096, 256, 0, stream>>>(s1, t, n1, kern, invU, rnv1);
    k_split2<<<1024, 256, 0, stream>>>(s2, invn2, ChT, ClT);
    k_gram_mfma<<<256, 256, 0, stream>>>(ChT, ClT, Gp);
    k_reduceG<<<1024, 256, 0, stream>>>(Gp, Gh, Gl);
    k_mavout<<<256, 256, 0, stream>>>(s1h, s1l, Gh, Gl, invU, rnv1, s1, kern, out);
}